// Round 3
// baseline (30.135 us; speedup 1.0000x reference)
//
#include <hip/hip_runtime.h>
#include <cmath>

#define BB 64
#define HH 64
#define WW 64
#define CI 16
#define CO 32
#define NIN 144           // 3*3*16

typedef __attribute__((ext_vector_type(8))) short s16x8;   // 8 bf16 (4 VGPRs)
typedef __attribute__((ext_vector_type(4))) float f32x4;

// RNE pack of two fp32 -> (lo, hi) bf16 in one u32
__device__ __forceinline__ unsigned pk_bf16(float a, float b) {
    unsigned ua = __float_as_uint(a);
    unsigned ub = __float_as_uint(b);
    ua = (ua + 0x7fffu + ((ua >> 16) & 1u)) >> 16;
    ub = (ub + 0x7fffu + ((ub >> 16) & 1u)) & 0xffff0000u;
    return ua | ub;
}

// ---------------------------------------------------------------------------
// Pre-kernel (ONE 832-thread block = 13 waves, all parallel):
//   waves 0..11 : B-fragments (bf16, exact mfma lane layout) at ws+128.
//                 frag f = 2*kstep + hf; column co = 2*(lane&15) + hf.
//   wave  12    : per-channel tables ws[0..31]=cosh(2r)/zn, ws[32..63]=sinh(2r),
//                 ws[64..95]=2*zn  (each channel split across 2 lanes + shfl).
// ---------------------------------------------------------------------------
__global__ void hyp_pre(const float* __restrict__ z, const float* __restrict__ r,
                        float* __restrict__ ws) {
    int t = threadIdx.x;
    if (t < 12 * 64) {
        int f = t >> 6, lane = t & 63;
        int s = f >> 1, hf = f & 1;
        int co = ((lane & 15) << 1) + hf;      // adjacent-channel mapping
        unsigned u[4];
#pragma unroll
        for (int jj = 0; jj < 4; ++jj) {
            int kp0 = s * 32 + (lane >> 4) * 8 + jj * 2;
            int row0 = kp0 >> 6, pos0 = kp0 & 63;
            float v0 = (pos0 < 48) ? z[(row0 * 48 + pos0) * CO + co] : 0.f;
            int kp1 = kp0 + 1;
            int row1 = kp1 >> 6, pos1 = kp1 & 63;
            float v1 = (pos1 < 48) ? z[(row1 * 48 + pos1) * CO + co] : 0.f;
            u[jj] = pk_bf16(v0, v1);
        }
        ((uint4*)(ws + 128))[t] = make_uint4(u[0], u[1], u[2], u[3]);
    } else {
        int u = t - 768;                       // 0..63, one full wave
        int co = u & 31, half = u >> 5;
        float s = 0.f;
        for (int k = half * 72; k < half * 72 + 72; ++k) {
            float v = z[k * CO + co];
            s = fmaf(v, v, s);
        }
        s += __shfl_xor(s, 32);                // combine k-halves
        if (half == 0) {
            float zn = fmaxf(sqrtf(s), 1e-7f);
            float tc = 2.0f * r[co];
            ws[co]          = coshf(tc) / zn;
            ws[CO + co]     = sinhf(tc);
            ws[2 * CO + co] = 2.0f * zn;
        }
    }
}

// ---------------------------------------------------------------------------
// Main kernel: block = (b, 4 rows x 64 cols), 4 waves, each wave 4 tiles of
// 16px x 32co via mfma_f32_16x16x32_bf16 (K'=192 -> 6 ksteps x 2 halves).
// x slab staged in LDS as bf16*ratio, ci halves split into 16B cells so the
// A-fragment ds_read_b128 is bank-conflict-free.
// ---------------------------------------------------------------------------
__global__ __launch_bounds__(256, 4) void hyp_main(
        const float* __restrict__ x,
        const float* __restrict__ ws,
        float* __restrict__ out,
        float ratio) {
    __shared__ __align__(16) unsigned short xsA[2][6][67][8];  // [ci-half][row][cell]
    __shared__ float qs[6][67];                                // per-cell sum x^2
    __shared__ float lam_ls[4][64];                            // lam * proj_scale
    __shared__ float lam_m1[4][64];                            // lam - 1
    __shared__ float pre_s[96];

    const int tid  = threadIdx.x;
    const int lane = tid & 63;
    const int wid  = tid >> 6;
    const int blk  = blockIdx.x;
    const int b    = blk >> 4;
    const int h0   = (blk & 15) << 2;

    const float ratio2 = ratio * ratio;

    // ---- stage x slab (rows h0-1..h0+4, cols -1..65, edge-clamped) ----
    for (int cell = tid; cell < 6 * 67; cell += 256) {
        int rr = cell / 67;
        int wi = cell - rr * 67;
        int gh = h0 - 1 + rr; gh = gh < 0 ? 0 : (gh > HH - 1 ? HH - 1 : gh);
        int gw = wi - 1;      gw = gw < 0 ? 0 : (gw > WW - 1 ? WW - 1 : gw);
        const float4* src = (const float4*)(x + ((((b << 6) + gh) << 6) + gw) * CI);
        float4 v0 = src[0], v1 = src[1], v2 = src[2], v3 = src[3];
        float q = 0.f;
        q = fmaf(v0.x, v0.x, q); q = fmaf(v0.y, v0.y, q);
        q = fmaf(v0.z, v0.z, q); q = fmaf(v0.w, v0.w, q);
        q = fmaf(v1.x, v1.x, q); q = fmaf(v1.y, v1.y, q);
        q = fmaf(v1.z, v1.z, q); q = fmaf(v1.w, v1.w, q);
        q = fmaf(v2.x, v2.x, q); q = fmaf(v2.y, v2.y, q);
        q = fmaf(v2.z, v2.z, q); q = fmaf(v2.w, v2.w, q);
        q = fmaf(v3.x, v3.x, q); q = fmaf(v3.y, v3.y, q);
        q = fmaf(v3.z, v3.z, q); q = fmaf(v3.w, v3.w, q);
        uint4 lo, hi;
        lo.x = pk_bf16(v0.x * ratio, v0.y * ratio);
        lo.y = pk_bf16(v0.z * ratio, v0.w * ratio);
        lo.z = pk_bf16(v1.x * ratio, v1.y * ratio);
        lo.w = pk_bf16(v1.z * ratio, v1.w * ratio);
        hi.x = pk_bf16(v2.x * ratio, v2.y * ratio);
        hi.y = pk_bf16(v2.z * ratio, v2.w * ratio);
        hi.z = pk_bf16(v3.x * ratio, v3.y * ratio);
        hi.w = pk_bf16(v3.z * ratio, v3.w * ratio);
        *(uint4*)&xsA[0][rr][wi][0] = lo;
        *(uint4*)&xsA[1][rr][wi][0] = hi;
        qs[rr][wi] = q;
    }

    // B-fragments: identical for every wave, L1/L2-resident
    s16x8 bf[12];
    {
        const uint4* fp = (const uint4*)(ws + 128);
#pragma unroll
        for (int f = 0; f < 12; ++f)
            bf[f] = __builtin_bit_cast(s16x8, fp[f * 64 + lane]);
    }
    if (tid < 96) pre_s[tid] = ws[tid];
    __syncthreads();

    // ---- per-pixel lambda / projection scale ----
    {
        int pr = tid >> 6;
        int w  = tid & 63;
        float s2 = 0.f;
#pragma unroll
        for (int kh = 0; kh < 3; ++kh)
#pragma unroll
            for (int kw = 0; kw < 3; ++kw)
                s2 += qs[pr + kh][w + kw];
        s2 *= ratio2;
        float yn = sqrtf(s2);
        float se = 1.0f;
        const float mn = 0.99999f;               // (1-1e-5)/sqrt(c)
        if (yn > mn) se = mn / fmaxf(yn, 1e-7f);
        float yn2 = s2 * se * se;
        float lam = 2.0f * __builtin_amdgcn_rcpf(fmaxf(1.0f - yn2, 1e-7f));
        lam_ls[pr][w] = lam * se;
        lam_m1[pr][w] = lam - 1.0f;
    }
    __syncthreads();

    const int col  = lane & 15;
    const int g    = lane >> 4;
    const int hsel = g & 1;                      // ci half for A reads
    const int kcE  = g >> 1;                     // kw cell for even ksteps
    const int c0i  = col << 1;                   // adjacent output channels
    const float cz0 = pre_s[c0i],      cz1 = pre_s[c0i + 1];
    const float sh0 = pre_s[32 + c0i], sh1 = pre_s[33 + c0i];
    const float tz0 = pre_s[64 + c0i], tz1 = pre_s[65 + c0i];

    for (int wc = 0; wc < 4; ++wc) {
        f32x4 acc0 = {0.f, 0.f, 0.f, 0.f};
        f32x4 acc1 = {0.f, 0.f, 0.f, 0.f};
#pragma unroll
        for (int s = 0; s < 6; ++s) {
            const int row = wid + (s >> 1);
            const int kc  = (s & 1) ? 2 : kcE;
            s16x8 a = {};
            if (!(s & 1) || g < 2)               // zero-pad tail 16 of each K-row
                a = *(const s16x8*)&xsA[hsel][row][wc * 16 + col + kc][0];
            acc0 = __builtin_amdgcn_mfma_f32_16x16x32_bf16(a, bf[2 * s],     acc0, 0, 0, 0);
            acc1 = __builtin_amdgcn_mfma_f32_16x16x32_bf16(a, bf[2 * s + 1], acc1, 0, 0, 0);
        }
        float* orow = out + ((((b << 6) + h0 + wid) << 6) + wc * 16) * CO;
#pragma unroll
        for (int i = 0; i < 4; ++i) {
            int pw = g * 4 + i;                  // pixel within the 16-tile
            float ls = lam_ls[wid][wc * 16 + pw];
            float lm = lam_m1[wid][wc * 16 + pw];
            float a0 = fmaf(ls * acc0[i], cz0, -(lm * sh0));
            float a1 = fmaf(ls * acc1[i], cz1, -(lm * sh1));
            // v = 2*zn*asinh(arg)
            float ax0 = fabsf(a0), ax1 = fabsf(a1);
            float v0 = copysignf(tz0 * __logf(ax0 + __builtin_amdgcn_sqrtf(fmaf(ax0, ax0, 1.f))), a0);
            float v1 = copysignf(tz1 * __logf(ax1 + __builtin_amdgcn_sqrtf(fmaf(ax1, ax1, 1.f))), a1);
            // v = 50*tanh(v/50)
            float e0 = __expf(fabsf(v0) * 0.04f);   // exp(2|v|/50)
            float e1 = __expf(fabsf(v1) * 0.04f);
            float t0 = copysignf(1.f - 2.f * __builtin_amdgcn_rcpf(e0 + 1.f), v0) * 50.f;
            float t1 = copysignf(1.f - 2.f * __builtin_amdgcn_rcpf(e1 + 1.f), v1) * 50.f;
            // w = sinh(v)
            float s0 = __expf(t0);
            float s1 = __expf(t1);
            float w0v = 0.5f * (s0 - __builtin_amdgcn_rcpf(s0));
            float w1v = 0.5f * (s1 - __builtin_amdgcn_rcpf(s1));
            // wn2 across all 32 co (16 lanes x 2 adjacent channels each)
            float wsq = fmaf(w0v, w0v, w1v * w1v);
            wsq += __shfl_xor(wsq, 1, 16);
            wsq += __shfl_xor(wsq, 2, 16);
            wsq += __shfl_xor(wsq, 4, 16);
            wsq += __shfl_xor(wsq, 8, 16);
            float inv = __builtin_amdgcn_rcpf(1.f + __builtin_amdgcn_sqrtf(1.f + wsq));
            float2 o;
            o.x = w0v * inv;
            o.y = w1v * inv;
            *(float2*)(orow + pw * CO + c0i) = o;   // dwordx2, 16 lanes = 128B run
        }
    }
}

// ---------------------------------------------------------------------------
extern "C" void kernel_launch(void* const* d_in, const int* in_sizes, int n_in,
                              void* d_out, int out_size, void* d_ws, size_t ws_size,
                              hipStream_t stream) {
    const float* x = (const float*)d_in[0];
    const float* z = (const float*)d_in[1];
    const float* r = (const float*)d_in[2];
    float* out = (float*)d_out;
    float* ws  = (float*)d_ws;

    double lb_n = lgamma(NIN / 2.0) + lgamma(0.5) - lgamma((NIN + 1) / 2.0);
    double lb_c = lgamma(CI  / 2.0) + lgamma(0.5) - lgamma((CI  + 1) / 2.0);
    float ratio = (float)exp(lb_n - lb_c);

    hyp_pre<<<1, 832, 0, stream>>>(z, r, ws);
    hyp_main<<<BB * (HH / 4), 256, 0, stream>>>(x, ws, out, ratio);
}

// Round 4
// 29.600 us; speedup vs baseline: 1.0181x; 1.0181x over previous
//
#include <hip/hip_runtime.h>
#include <cmath>

#define BB 64
#define HH 64
#define WW 64
#define CI 16
#define CO 32
#define NIN 144           // 3*3*16

typedef __attribute__((ext_vector_type(8))) short s16x8;   // 8 bf16 (4 VGPRs)
typedef __attribute__((ext_vector_type(4))) float f32x4;

// RNE pack of two fp32 -> (lo, hi) bf16 in one u32
__device__ __forceinline__ unsigned pk_bf16(float a, float b) {
    unsigned ua = __float_as_uint(a);
    unsigned ub = __float_as_uint(b);
    ua = (ua + 0x7fffu + ((ua >> 16) & 1u)) >> 16;
    ub = (ub + 0x7fffu + ((ub >> 16) & 1u)) & 0xffff0000u;
    return ua | ub;
}

// ---------------------------------------------------------------------------
// Pre-kernel (ONE 832-thread block = 13 waves, all parallel):
//   waves 0..11 : B-fragments (bf16, exact mfma lane layout) at ws+128.
//                 frag f = 2*kstep + hf; column co = 2*(lane&15) + hf.
//   wave  12    : per-channel tables ws[0..31]=cosh(2r)/zn, ws[32..63]=sinh(2r),
//                 ws[64..95]=2*zn.
// ---------------------------------------------------------------------------
__global__ void hyp_pre(const float* __restrict__ z, const float* __restrict__ r,
                        float* __restrict__ ws) {
    int t = threadIdx.x;
    if (t < 12 * 64) {
        int f = t >> 6, lane = t & 63;
        int s = f >> 1, hf = f & 1;
        int co = ((lane & 15) << 1) + hf;      // adjacent-channel mapping
        unsigned u[4];
#pragma unroll
        for (int jj = 0; jj < 4; ++jj) {
            int kp0 = s * 32 + (lane >> 4) * 8 + jj * 2;
            int row0 = kp0 >> 6, pos0 = kp0 & 63;
            float v0 = (pos0 < 48) ? z[(row0 * 48 + pos0) * CO + co] : 0.f;
            int kp1 = kp0 + 1;
            int row1 = kp1 >> 6, pos1 = kp1 & 63;
            float v1 = (pos1 < 48) ? z[(row1 * 48 + pos1) * CO + co] : 0.f;
            u[jj] = pk_bf16(v0, v1);
        }
        ((uint4*)(ws + 128))[t] = make_uint4(u[0], u[1], u[2], u[3]);
    } else {
        int u = t - 768;                       // 0..63, one full wave
        int co = u & 31, half = u >> 5;
        float s = 0.f;
        for (int k = half * 72; k < half * 72 + 72; ++k) {
            float v = z[k * CO + co];
            s = fmaf(v, v, s);
        }
        s += __shfl_xor(s, 32);                // combine k-halves
        if (half == 0) {
            float zn = fmaxf(sqrtf(s), 1e-7f);
            float tc = 2.0f * r[co];
            ws[co]          = coshf(tc) / zn;
            ws[CO + co]     = sinhf(tc);
            ws[2 * CO + co] = 2.0f * zn;
        }
    }
}

// ---------------------------------------------------------------------------
// Main kernel: ONE OUTPUT ROW per block (b, h, 64 cols); grid = 4096 blocks =
// 4 resident generations -> staging of later blocks pipelines under compute/
// stores of earlier ones. XCD-chunked swizzle keeps each XCD on 8 whole
// images so the 3x halo re-read of x is an L2 hit.
// Wave w computes the 16-px tile at cols [w*16, w*16+16) x all 32 co.
// ---------------------------------------------------------------------------
__global__ __launch_bounds__(256, 4) void hyp_main(
        const float* __restrict__ x,
        const float* __restrict__ ws,
        float* __restrict__ out,
        float ratio) {
    __shared__ __align__(16) unsigned short xsA[2][3][67][8];  // [ci-half][row][cell]
    __shared__ float qs[3][67];                                // per-cell sum x^2
    __shared__ float lam_ls[64];                               // lam * proj_scale
    __shared__ float lam_m1[64];                               // lam - 1
    __shared__ float pre_s[96];

    const int tid  = threadIdx.x;
    const int lane = tid & 63;
    const int wid  = tid >> 6;

    // XCD-chunked bijective swizzle: XCD i owns logical rows [i*512,(i+1)*512)
    const int bid = blockIdx.x;
    const int lid = ((bid & 7) << 9) | (bid >> 3);
    const int b   = lid >> 6;
    const int h   = lid & 63;

    // B-fragments: identical for every wave, hot in L1/L2
    s16x8 bf[12];
    {
        const uint4* fp = (const uint4*)(ws + 128);
#pragma unroll
        for (int f = 0; f < 12; ++f)
            bf[f] = __builtin_bit_cast(s16x8, fp[f * 64 + lane]);
    }
    if (tid < 96) pre_s[tid] = ws[tid];

    const float ratio2 = ratio * ratio;

    // ---- stage x slab (rows h-1..h+1, cols -1..65, edge-clamped) ----
    if (tid < 3 * 67) {
        int rr = tid / 67;
        int wi = tid - rr * 67;
        int gh = h - 1 + rr; gh = gh < 0 ? 0 : (gh > HH - 1 ? HH - 1 : gh);
        int gw = wi - 1;     gw = gw < 0 ? 0 : (gw > WW - 1 ? WW - 1 : gw);
        const float4* src = (const float4*)(x + ((((b << 6) + gh) << 6) + gw) * CI);
        float4 v0 = src[0], v1 = src[1], v2 = src[2], v3 = src[3];
        float q = 0.f;
        q = fmaf(v0.x, v0.x, q); q = fmaf(v0.y, v0.y, q);
        q = fmaf(v0.z, v0.z, q); q = fmaf(v0.w, v0.w, q);
        q = fmaf(v1.x, v1.x, q); q = fmaf(v1.y, v1.y, q);
        q = fmaf(v1.z, v1.z, q); q = fmaf(v1.w, v1.w, q);
        q = fmaf(v2.x, v2.x, q); q = fmaf(v2.y, v2.y, q);
        q = fmaf(v2.z, v2.z, q); q = fmaf(v2.w, v2.w, q);
        q = fmaf(v3.x, v3.x, q); q = fmaf(v3.y, v3.y, q);
        q = fmaf(v3.z, v3.z, q); q = fmaf(v3.w, v3.w, q);
        uint4 lo, hi;
        lo.x = pk_bf16(v0.x * ratio, v0.y * ratio);
        lo.y = pk_bf16(v0.z * ratio, v0.w * ratio);
        lo.z = pk_bf16(v1.x * ratio, v1.y * ratio);
        lo.w = pk_bf16(v1.z * ratio, v1.w * ratio);
        hi.x = pk_bf16(v2.x * ratio, v2.y * ratio);
        hi.y = pk_bf16(v2.z * ratio, v2.w * ratio);
        hi.z = pk_bf16(v3.x * ratio, v3.y * ratio);
        hi.w = pk_bf16(v3.z * ratio, v3.w * ratio);
        *(uint4*)&xsA[0][rr][wi][0] = lo;
        *(uint4*)&xsA[1][rr][wi][0] = hi;
        qs[rr][wi] = q;
    }
    __syncthreads();

    // ---- per-pixel lambda / projection scale (one thread per pixel) ----
    if (tid < 64) {
        float s2 = 0.f;
#pragma unroll
        for (int rr = 0; rr < 3; ++rr)
#pragma unroll
            for (int kw = 0; kw < 3; ++kw)
                s2 += qs[rr][tid + kw];
        s2 *= ratio2;
        float yn = sqrtf(s2);
        float se = 1.0f;
        const float mn = 0.99999f;               // (1-1e-5)/sqrt(c)
        if (yn > mn) se = mn / fmaxf(yn, 1e-7f);
        float yn2 = s2 * se * se;
        float lam = 2.0f * __builtin_amdgcn_rcpf(fmaxf(1.0f - yn2, 1e-7f));
        lam_ls[tid] = lam * se;
        lam_m1[tid] = lam - 1.0f;
    }
    __syncthreads();

    const int col  = lane & 15;
    const int g    = lane >> 4;
    const int hsel = g & 1;                      // ci half for A reads
    const int kcE  = g >> 1;                     // kw cell for even ksteps
    const int c0i  = col << 1;                   // adjacent output channels
    const float cz0 = pre_s[c0i],      cz1 = pre_s[c0i + 1];
    const float sh0 = pre_s[32 + c0i], sh1 = pre_s[33 + c0i];
    const float tz0 = pre_s[64 + c0i], tz1 = pre_s[65 + c0i];

    f32x4 acc0 = {0.f, 0.f, 0.f, 0.f};
    f32x4 acc1 = {0.f, 0.f, 0.f, 0.f};
#pragma unroll
    for (int s = 0; s < 6; ++s) {
        const int row = s >> 1;
        const int kc  = (s & 1) ? 2 : kcE;
        s16x8 a = {};
        if (!(s & 1) || g < 2)                   // zero-pad tail 16 of each K-row
            a = *(const s16x8*)&xsA[hsel][row][(wid << 4) + col + kc][0];
        acc0 = __builtin_amdgcn_mfma_f32_16x16x32_bf16(a, bf[2 * s],     acc0, 0, 0, 0);
        acc1 = __builtin_amdgcn_mfma_f32_16x16x32_bf16(a, bf[2 * s + 1], acc1, 0, 0, 0);
    }

    float* orow = out + ((((b << 6) + h) << 6) + (wid << 4)) * CO;
#pragma unroll
    for (int i = 0; i < 4; ++i) {
        int pw = (g << 2) + i;                   // pixel within the 16-tile
        float ls = lam_ls[(wid << 4) + pw];
        float lm = lam_m1[(wid << 4) + pw];
        float a0 = fmaf(ls * acc0[i], cz0, -(lm * sh0));
        float a1 = fmaf(ls * acc1[i], cz1, -(lm * sh1));
        // v = 2*zn*asinh(arg)
        float ax0 = fabsf(a0), ax1 = fabsf(a1);
        float v0 = copysignf(tz0 * __logf(ax0 + __builtin_amdgcn_sqrtf(fmaf(ax0, ax0, 1.f))), a0);
        float v1 = copysignf(tz1 * __logf(ax1 + __builtin_amdgcn_sqrtf(fmaf(ax1, ax1, 1.f))), a1);
        // v = 50*tanh(v/50)
        float e0 = __expf(fabsf(v0) * 0.04f);    // exp(2|v|/50)
        float e1 = __expf(fabsf(v1) * 0.04f);
        float t0 = copysignf(1.f - 2.f * __builtin_amdgcn_rcpf(e0 + 1.f), v0) * 50.f;
        float t1 = copysignf(1.f - 2.f * __builtin_amdgcn_rcpf(e1 + 1.f), v1) * 50.f;
        // w = sinh(v)
        float s0 = __expf(t0);
        float s1 = __expf(t1);
        float w0v = 0.5f * (s0 - __builtin_amdgcn_rcpf(s0));
        float w1v = 0.5f * (s1 - __builtin_amdgcn_rcpf(s1));
        // wn2 across all 32 co (16 lanes x 2 adjacent channels each)
        float wsq = fmaf(w0v, w0v, w1v * w1v);
        wsq += __shfl_xor(wsq, 1, 16);
        wsq += __shfl_xor(wsq, 2, 16);
        wsq += __shfl_xor(wsq, 4, 16);
        wsq += __shfl_xor(wsq, 8, 16);
        float inv = __builtin_amdgcn_rcpf(1.f + __builtin_amdgcn_sqrtf(1.f + wsq));
        float2 o;
        o.x = w0v * inv;
        o.y = w1v * inv;
        *(float2*)(orow + pw * CO + c0i) = o;    // 16 lanes = 128B contiguous
    }
}

// ---------------------------------------------------------------------------
extern "C" void kernel_launch(void* const* d_in, const int* in_sizes, int n_in,
                              void* d_out, int out_size, void* d_ws, size_t ws_size,
                              hipStream_t stream) {
    const float* x = (const float*)d_in[0];
    const float* z = (const float*)d_in[1];
    const float* r = (const float*)d_in[2];
    float* out = (float*)d_out;
    float* ws  = (float*)d_ws;

    double lb_n = lgamma(NIN / 2.0) + lgamma(0.5) - lgamma((NIN + 1) / 2.0);
    double lb_c = lgamma(CI  / 2.0) + lgamma(0.5) - lgamma((CI  + 1) / 2.0);
    float ratio = (float)exp(lb_n - lb_c);

    hyp_pre<<<1, 832, 0, stream>>>(z, r, ws);
    hyp_main<<<BB * HH, 256, 0, stream>>>(x, ws, out, ratio);
}